// Round 10
// baseline (99.972 us; speedup 1.0000x reference)
//
#include <hip/hip_runtime.h>
#include <hip/hip_bf16.h>

#define B_ 8
#define N_ 4096   // H*W
#define C_ 128
#define EPSV 1e-5f
#define SPLIT 3
#define KVB 32

using bf8   = __attribute__((ext_vector_type(8))) short;   // 8 bf16 (4 VGPRs)
using u16x8 = __attribute__((ext_vector_type(8))) ushort;
using f32x4 = __attribute__((ext_vector_type(4))) float;   // MFMA C/D

__device__ __forceinline__ ushort f2b(float f) {
  __hip_bfloat16 h = __float2bfloat16(f);
  return *reinterpret_cast<ushort*>(&h);
}
__device__ __forceinline__ float b2f(ushort u) {
  union { float f; unsigned x; } t; t.x = ((unsigned)u) << 16; return t.f;
}

// async global->LDS, 16B per lane; LDS dest is wave-uniform base + lane*16
__device__ __forceinline__ void gll16(const void* g, void* l) {
  __builtin_amdgcn_global_load_lds((const __attribute__((address_space(1))) void*)g,
                                   (__attribute__((address_space(3))) void*)l,
                                   16, 0, 0);
}

// ---------------- merged: GroupNorm partial stats + weight transpose ----------------
// blockIdx.y < 64: gn-partial path (bg = y, chunk = x)
// blockIdx.y >= 64: wtrans path, widx = y-64: wt[widx][n][el(k,n)] = bf16(w[k][n])
__global__ __launch_bounds__(256) void gnw(const float* __restrict__ x,
                                           const float* __restrict__ wq,
                                           const float* __restrict__ wk,
                                           const float* __restrict__ wv,
                                           const float* __restrict__ wp,
                                           float2* __restrict__ part,
                                           ushort* __restrict__ wt) {
  if (blockIdx.y >= 64) {
    const int widx = blockIdx.y - 64;
    const float* w = (widx == 0) ? wq : (widx == 1) ? wk : (widx == 2) ? wv : wp;
    ushort* o = wt + widx * 16384;
    const int r  = blockIdx.x * 16 + (threadIdx.x >> 4);   // k row 0..127
    const int c0 = (threadIdx.x & 15) << 3;                // n col base
    const float4 v0 = *reinterpret_cast<const float4*>(w + (size_t)r * C_ + c0);
    const float4 v1 = *reinterpret_cast<const float4*>(w + (size_t)r * C_ + c0 + 4);
    const float vv[8] = {v0.x, v0.y, v0.z, v0.w, v1.x, v1.y, v1.z, v1.w};
    #pragma unroll
    for (int j = 0; j < 8; ++j) {
      const int n = c0 + j;
      const int el = (r & 7) | ((((r >> 3)) ^ (n & 7)) << 3);
      o[(size_t)n * C_ + el] = f2b(vv[j]);
    }
    return;
  }
  const int bg = blockIdx.y;           // 0..63  (b*8+g)
  const int b = bg >> 3, g = bg & 7;
  const int chunk = blockIdx.x;        // 0..7
  const float* xp = x + (size_t)b * N_ * C_ + g * 16;
  float s = 0.f, s2 = 0.f;
  const int base4 = chunk * 2048;      // float4 index base
  for (int i = threadIdx.x; i < 2048; i += 256) {
    const int idx = base4 + i;
    const int n = idx >> 2, c4 = (idx & 3) << 2;
    const float4 v = *reinterpret_cast<const float4*>(xp + (size_t)n * C_ + c4);
    s  += v.x + v.y + v.z + v.w;
    s2 += v.x*v.x + v.y*v.y + v.z*v.z + v.w*v.w;
  }
  #pragma unroll
  for (int off = 32; off; off >>= 1) { s += __shfl_down(s, off); s2 += __shfl_down(s2, off); }
  __shared__ float red[8];
  const int wid = threadIdx.x >> 6;
  if ((threadIdx.x & 63) == 0) { red[wid] = s; red[4 + wid] = s2; }
  __syncthreads();
  if (threadIdx.x == 0)
    part[bg * 8 + chunk] = make_float2(red[0]+red[1]+red[2]+red[3],
                                       red[4]+red[5]+red[6]+red[7]);
}

// per-block inline group stats: mrs[g*2] = mean, mrs[g*2+1] = rsqrt(var+eps)
__device__ __forceinline__ void block_mrs(const float2* part, int b, int tid,
                                          float2* sp, float* mrs) {
  if (tid < 64) sp[tid] = part[b * 64 + tid];
  __syncthreads();
  if (tid < 8) {
    float s = 0.f, s2 = 0.f;
    #pragma unroll
    for (int c = 0; c < 8; ++c) { s += sp[tid*8+c].x; s2 += sp[tid*8+c].y; }
    const float inv = 1.f / 65536.f;
    const float m = s * inv;
    const float var = s2 * inv - m * m;
    mrs[tid*2]   = m;
    mrs[tid*2+1] = rsqrtf(var + EPSV);
  }
  __syncthreads();
}

// ---------------- fused GN + QKV projection (64-row tiles, 512 blocks) ----------------
// vtb is written with the kv axis PRE-PERMUTED within each 32-kv tile:
// o = hi*16 + lk*4 + r  ->  o' = lk*8 + hi*4 + r  (bits [4]=hi [3:2]=lk [1:0]=r
//   -> [4:3]=lk [2]=hi [1:0]=r; r bits untouched so 4-elem stores stay contiguous)
// so attention's PV A-fragment maps to one contiguous 16B LDS granule.
// ALSO stores gn(x) as bf16 (xnb) so proj_res skips the x re-read + GN recompute.
__global__ __launch_bounds__(256) void qkv_fused(const float* __restrict__ x,
                                                 const float2* __restrict__ part,
                                                 const float* __restrict__ gamma,
                                                 const float* __restrict__ beta,
                                                 const ushort* __restrict__ wt,
                                                 const float* __restrict__ bq,
                                                 const float* __restrict__ bk,
                                                 const float* __restrict__ bv,
                                                 ushort* __restrict__ qb, ushort* __restrict__ kb,
                                                 ushort* __restrict__ vtb,
                                                 ushort* __restrict__ xnb) {
  __shared__ ushort A[64][128];    // gn(x) tile, swizzled (octet ^= row&7)
  __shared__ ushort Bt[128][128];  // Bt[n][k] = w[k][n], swizzled
  __shared__ float2 sp[64];
  __shared__ float mrs[16];
  const int m0 = blockIdx.x * 64;
  const int tid = threadIdx.x;
  const int wid = tid >> 6, lane = tid & 63;
  block_mrs(part, m0 >> 12, tid, sp, mrs);
  for (int i = tid; i < 1024; i += 256) {
    const int row = i >> 4, c = (i & 15) << 3;
    const int grow = m0 + row;
    const float mm = mrs[(c >> 4) * 2], rr = mrs[(c >> 4) * 2 + 1];
    const float4 v0 = *reinterpret_cast<const float4*>(&x[(size_t)grow * C_ + c]);
    const float4 v1 = *reinterpret_cast<const float4*>(&x[(size_t)grow * C_ + c + 4]);
    const float vv[8] = {v0.x, v0.y, v0.z, v0.w, v1.x, v1.y, v1.z, v1.w};
    u16x8 u;
    #pragma unroll
    for (int j = 0; j < 8; ++j)
      u[j] = f2b((vv[j] - mm) * rr * gamma[c+j] + beta[c+j]);
    *reinterpret_cast<u16x8*>(&xnb[(size_t)grow * C_ + c]) = u;   // forward gn(x)
    const int el = ((c >> 3) ^ (row & 7)) << 3;
    *reinterpret_cast<u16x8*>(&A[row][el]) = u;
  }
  const int wm = wid >> 1, wn = wid & 1;
  const int lr = lane & 15, lk = lane >> 4;
  // 128^-0.5 * log2(e) folded into q (attention uses exp2)
  const float qscale = 0.12751749f;

  #pragma unroll 1
  for (int j = 0; j < 3; ++j) {
    const ushort* wtj = wt + j * 16384;       // [n][k] bf16, pre-swizzled
    const float* bias = (j == 0) ? bq : (j == 1) ? bk : bv;
    __syncthreads();   // previous compute's Bt reads done (A stage done on j=0)
    {
      ushort* bt0 = &Bt[0][0];
      #pragma unroll
      for (int c8 = 0; c8 < 8; ++c8) {
        const int ch = wid * 8 + c8;          // 32 chunks of 1KB
        gll16(wtj + ch * 512 + lane * 8, bt0 + ch * 512);
      }
    }
    __syncthreads();
    f32x4 acc[2][4] = {};
    #pragma unroll
    for (int ks = 0; ks < 4; ++ks) {
      const int g0 = ks * 4 + lk;
      bf8 af[2], bfv[4];
      #pragma unroll
      for (int mi = 0; mi < 2; ++mi) {
        const int row = wm * 32 + mi * 16 + lr;
        af[mi] = *reinterpret_cast<const bf8*>(&A[row][(g0 ^ (row & 7)) << 3]);
      }
      #pragma unroll
      for (int ni = 0; ni < 4; ++ni) {
        const int n = wn * 64 + ni * 16 + lr;
        bfv[ni] = *reinterpret_cast<const bf8*>(&Bt[n][(g0 ^ (n & 7)) << 3]);
      }
      #pragma unroll
      for (int mi = 0; mi < 2; ++mi)
        #pragma unroll
        for (int ni = 0; ni < 4; ++ni)
          acc[mi][ni] = __builtin_amdgcn_mfma_f32_16x16x32_bf16(af[mi], bfv[ni], acc[mi][ni], 0, 0, 0);
    }
    if (j < 2) {
      ushort* out = (j == 0) ? qb : kb;
      const float sc = (j == 0) ? qscale : 1.0f;
      #pragma unroll
      for (int mi = 0; mi < 2; ++mi)
        #pragma unroll
        for (int ni = 0; ni < 4; ++ni)
          #pragma unroll
          for (int r = 0; r < 4; ++r) {
            const int row = m0 + wm * 32 + mi * 16 + lk * 4 + r;
            const int col = wn * 64 + ni * 16 + lr;
            out[(size_t)row * C_ + col] = f2b((acc[mi][ni][r] + bias[col]) * sc);
          }
    } else {
      #pragma unroll
      for (int mi = 0; mi < 2; ++mi)
        #pragma unroll
        for (int ni = 0; ni < 4; ++ni) {
          const int rowb = m0 + wm * 32 + mi * 16 + lk * 4;
          const int col  = wn * 64 + ni * 16 + lr;
          const int bb = rowb >> 12, nn = rowb & 4095;
          // pi-permute kv within its 32-tile (verified in round 7)
          const int o  = nn & 31;
          const int op = (o & 3) | ((o & 0x0C) << 1) | ((o & 0x10) >> 2);
          const int nnp = (nn & ~31) | op;
          const float bv2 = bias[col];
          ushort4 u;
          u.x = f2b(acc[mi][ni][0] + bv2);
          u.y = f2b(acc[mi][ni][1] + bv2);
          u.z = f2b(acc[mi][ni][2] + bv2);
          u.w = f2b(acc[mi][ni][3] + bv2);
          *reinterpret_cast<ushort4*>(&vtb[((size_t)bb * C_ + col) * N_ + nnp]) = u;
        }
    }
  }
}

// ---------------- Flash attention (no-max exp2, kv-split, 3 blocks/CU) ----------------
// Occupancy WITHOUT the prior taxes: KVB 64->32 at UNCHANGED 32 q-rows/wave
// (both reuse ratios preserved: 2 MFMA per K-read and per V-read — R7 lesson),
// K+V both distance-1 double-buffered (R5 lesson), LDS 32KB -> 3 blocks/CU via
// SPLIT=3 (grid 768, 3 waves/SIMD). The R5/R8 SPLIT write-amplification is
// killed by the COALESCED O-store epilogue: O is bounced through LDS (reusing
// the K/V buffers post-loop) and stored as full 128B-line u16x8 runs instead
// of 32B partial-line scatters.
// LDS map (ushort offs): K0@0 K1@4096 V0@8192 V1@12288 (32KB); epilogue reuses
// all 32KB as the [128][128] bf16 O tile.
__global__ __launch_bounds__(256, 3) void attn_fwd(const ushort* __restrict__ q,
                                                   const ushort* __restrict__ k,
                                                   const ushort* __restrict__ vt,
                                                   ushort* __restrict__ Op,
                                                   float* __restrict__ lsum) {
  extern __shared__ ushort smem[];
  const int bid = blockIdx.x;
  const int b   = bid & 7;            // batch == XCD (dispatch round-robin i%8)
  const int qi  = (bid >> 3) & 31;
  const int z   = bid >> 8;           // 0..SPLIT-1 (grid 768)
  const int q0  = qi * 128;
  const int tid = threadIdx.x;
  const int w = tid >> 6, lane = tid & 63;
  const int lr = lane & 15, lk = lane >> 4;
  const ushort* qb = q  + (size_t)b * N_ * C_;
  const ushort* kb = k  + (size_t)b * N_ * C_;
  const ushort* vb = vt + (size_t)b * C_ * N_;   // [d][n-permuted]

  bf8 qf[2][4];
  #pragma unroll
  for (int h = 0; h < 2; ++h) {
    const int qrow = q0 + w * 32 + h * 16 + lr;
    #pragma unroll
    for (int ks = 0; ks < 4; ++ks)
      qf[h][ks] = *reinterpret_cast<const bf8*>(&qb[(size_t)qrow * C_ + ks * 32 + lk * 8]);
  }

  bf8 onesf;
  #pragma unroll
  for (int j = 0; j < 8; ++j) onesf[j] = (short)0x3F80;   // bf16 1.0

  f32x4 oacc[2][8] = {};
  f32x4 accl[2] = {};                 // l-sums via mfma(P, ones)

  const int t0 = (z * 128) / SPLIT;   // 128 kv-tiles of 32: 0,42,85
  const int t1 = ((z + 1) * 128) / SPLIT;

  // strength-reduced staging pointers (computed once, +const stride per tile)
  // K tile: 32 rows x 256B = 8 chunks of 1KB; V tile: paired-row layout (R7).
  const ushort* kg[2];
  const ushort* vg[2];
  #pragma unroll
  for (int j = 0; j < 2; ++j) {
    const int m = w * 2 + j;              // chunk 0..7
    const int krow = m * 4 + (lane >> 4); // 0..31
    kg[j] = kb + (size_t)(t0 * KVB + krow) * C_ + (((lane & 15) ^ (krow & 7)) << 3);
    const int dd = m * 8 + (lane >> 3);   // 0..63
    const int sl = lane & 7;
    const int d  = dd * 2 + (sl >> 2);
    const int g  = (sl & 3) ^ (dd & 3);
    vg[j] = vb + (size_t)d * N_ + t0 * KVB + g * 8;
  }

  auto STAGE = [&](int sel) {
    ushort* Kd = smem + sel * 4096;
    ushort* Vd = smem + 8192 + sel * 4096;
    #pragma unroll
    for (int j = 0; j < 2; ++j) {
      const int m = w * 2 + j;
      gll16(kg[j], Kd + m * 512);
      gll16(vg[j], Vd + m * 512);
    }
    #pragma unroll
    for (int j = 0; j < 2; ++j) { kg[j] += KVB * C_; vg[j] += KVB; }
  };

  STAGE(0);
  __builtin_amdgcn_s_setprio(1);
  #pragma unroll 1
  for (int kt = t0; kt < t1; ++kt) {
    const int cur = (kt - t0) & 1;
    // barrier: drains last iter's stage loads (in flight for a full compute
    // phase) and guarantees all waves done reading the buffer we stage next.
    __syncthreads();
    if (kt + 1 < t1) STAGE(cur ^ 1);

    const ushort* Kc = smem + cur * 4096;
    const ushort* Vc = smem + 8192 + cur * 4096;

    // S^T = K Q^T  (swapped operands: lane holds 4 consecutive kv per q-col)
    f32x4 s[2][2] = {};
    #pragma unroll
    for (int ks = 0; ks < 4; ++ks) {
      const int g0 = ks * 4 + lk;
      bf8 kf[2];
      #pragma unroll
      for (int ni = 0; ni < 2; ++ni) {
        const int n = ni * 16 + lr;
        kf[ni] = *reinterpret_cast<const bf8*>(&Kc[n * 128 + ((g0 ^ (n & 7)) << 3)]);
      }
      #pragma unroll
      for (int h = 0; h < 2; ++h)
        #pragma unroll
        for (int ni = 0; ni < 2; ++ni)
          s[h][ni] = __builtin_amdgcn_mfma_f32_16x16x32_bf16(kf[ni], qf[h][ks], s[h][ni], 0, 0, 0);
    }

    // P = exp2(S) in-register -> one PV A-fragment per h (pi order matches vtb):
    // elem j = hi*4+r <- exp2(s[h][hi][r])  (kv = hi*16 + lk*4 + r)
    bf8 pa[2];
    #pragma unroll
    for (int h = 0; h < 2; ++h) {
      bf8 t;
      #pragma unroll
      for (int hi = 0; hi < 2; ++hi) {
        const f32x4 sv = s[h][hi];
        #pragma unroll
        for (int r = 0; r < 4; ++r)
          t[hi * 4 + r] = (short)f2b(__builtin_amdgcn_exp2f(sv[r]));
      }
      pa[h] = t;
    }
    #pragma unroll
    for (int h = 0; h < 2; ++h)
      accl[h] = __builtin_amdgcn_mfma_f32_16x16x32_bf16(pa[h], onesf, accl[h], 0, 0, 0);

    // O += P V  (single b128 V read per ni, paired-row layout, granule g=lk)
    #pragma unroll
    for (int ni = 0; ni < 8; ++ni) {
      const int d = ni * 16 + lr;
      const int off = (d >> 1) * 64 + ((((d & 1) << 2) | (lk ^ ((d >> 1) & 3))) << 3);
      const bf8 vf = *reinterpret_cast<const bf8*>(&Vc[off]);
      #pragma unroll
      for (int h = 0; h < 2; ++h)
        oacc[h][ni] = __builtin_amdgcn_mfma_f32_16x16x32_bf16(pa[h], vf, oacc[h][ni], 0, 0, 0);
    }
  }
  __builtin_amdgcn_s_setprio(0);

  // l-sum lives in accl[h][r] for q-row lk*4+r (all lr cols identical)
  const size_t zb = (size_t)(z * B_ + b);
  if (lr == 0) {
    #pragma unroll
    for (int h = 0; h < 2; ++h)
      #pragma unroll
      for (int r = 0; r < 4; ++r)
        lsum[zb * N_ + q0 + w * 32 + h * 16 + lk * 4 + r] = accl[h][r];
  }

  // ---- coalesced O-store: bounce through LDS (reuse K/V buffers) ----
  __syncthreads();   // all waves done with V[cur]; smem reusable as [128][128] bf16
  #pragma unroll
  for (int h = 0; h < 2; ++h)
    #pragma unroll
    for (int ni = 0; ni < 8; ++ni) {
      const int gc = ni * 2 + (lr >> 3);          // 16B granule 0..15
      #pragma unroll
      for (int r = 0; r < 4; ++r) {
        const int row = w * 32 + h * 16 + lk * 4 + r;   // 0..127
        smem[row * 128 + ((gc ^ (row & 7)) << 3) + (lr & 7)] = f2b(oacc[h][ni][r]);
      }
    }
  __syncthreads();
  ushort* ob = Op + zb * N_ * C_ + (size_t)q0 * C_;
  #pragma unroll
  for (int p = 0; p < 8; ++p) {
    const int i = p * 256 + tid;                  // 16B chunk index 0..2047
    const int row = i >> 4, g = i & 15;
    const u16x8 v = *reinterpret_cast<const u16x8*>(&smem[row * 128 + ((g ^ (row & 7)) << 3)]);
    *reinterpret_cast<u16x8*>(&ob[(size_t)row * C_ + g * 8]) = v;
  }
}

// ---------------- output projection + residual (64-row tiles, combines partials) ----------------
// Residual xn comes from the forwarded bf16 xnb (written by qkv_fused).
__global__ __launch_bounds__(256) void proj_res(const ushort* __restrict__ Op,
                                                const float* __restrict__ lsum,
                                                const ushort* __restrict__ wtp,
                                                const float* __restrict__ bias,
                                                const ushort* __restrict__ xnb,
                                                float* __restrict__ outp) {
  __shared__ ushort A[64][128];
  __shared__ ushort Bt[128][128];
  const int m0 = blockIdx.x * 64;
  const int tid = threadIdx.x;
  const int wid = tid >> 6, lane = tid & 63;
  const size_t BN = (size_t)B_ * N_;
  {
    ushort* bt0 = &Bt[0][0];
    #pragma unroll
    for (int c8 = 0; c8 < 8; ++c8) {
      const int ch = wid * 8 + c8;          // 32 chunks of 1KB
      gll16(wtp + ch * 512 + lane * 8, bt0 + ch * 512);
    }
  }
  for (int i = tid; i < 1024; i += 256) {
    const int row = i >> 4, c = (i & 15) << 3;
    const size_t grow = m0 + row;
    float l = 0.f;
    #pragma unroll
    for (int zz = 0; zz < SPLIT; ++zz) l += lsum[zz * BN + grow];
    const float inv = 1.f / l;
    float acc8[8] = {};
    #pragma unroll
    for (int zz = 0; zz < SPLIT; ++zz) {
      const u16x8 a = *reinterpret_cast<const u16x8*>(&Op[(zz * BN + grow) * C_ + c]);
      #pragma unroll
      for (int j = 0; j < 8; ++j) acc8[j] += b2f(a[j]);
    }
    u16x8 u;
    #pragma unroll
    for (int j = 0; j < 8; ++j) u[j] = f2b(acc8[j] * inv);
    const int el = ((c >> 3) ^ (row & 7)) << 3;
    *reinterpret_cast<u16x8*>(&A[row][el]) = u;
  }
  __syncthreads();
  const int wm = wid >> 1, wn = wid & 1;
  const int lr = lane & 15, lk = lane >> 4;
  f32x4 acc[2][4] = {};
  #pragma unroll
  for (int ks = 0; ks < 4; ++ks) {
    const int g0 = ks * 4 + lk;
    bf8 af[2], bfv[4];
    #pragma unroll
    for (int mi = 0; mi < 2; ++mi) {
      const int row = wm * 32 + mi * 16 + lr;
      af[mi] = *reinterpret_cast<const bf8*>(&A[row][(g0 ^ (row & 7)) << 3]);
    }
    #pragma unroll
    for (int ni = 0; ni < 4; ++ni) {
      const int n = wn * 64 + ni * 16 + lr;
      bfv[ni] = *reinterpret_cast<const bf8*>(&Bt[n][(g0 ^ (n & 7)) << 3]);
    }
    #pragma unroll
    for (int mi = 0; mi < 2; ++mi)
      #pragma unroll
      for (int ni = 0; ni < 4; ++ni)
        acc[mi][ni] = __builtin_amdgcn_mfma_f32_16x16x32_bf16(af[mi], bfv[ni], acc[mi][ni], 0, 0, 0);
  }
  #pragma unroll
  for (int mi = 0; mi < 2; ++mi)
    #pragma unroll
    for (int ni = 0; ni < 4; ++ni) {
      const int col = wn * 64 + ni * 16 + lr;
      const float bia = bias[col];
      #pragma unroll
      for (int r = 0; r < 4; ++r) {
        const int row = m0 + wm * 32 + mi * 16 + lk * 4 + r;
        const float xn = b2f(xnb[(size_t)row * C_ + col]);
        outp[(size_t)row * C_ + col] = xn + acc[mi][ni][r] + bia;
      }
    }
}

extern "C" void kernel_launch(void* const* d_in, const int* in_sizes, int n_in,
                              void* d_out, int out_size, void* d_ws, size_t ws_size,
                              hipStream_t stream) {
  const float* x     = (const float*)d_in[0];
  const float* gamma = (const float*)d_in[1];
  const float* beta  = (const float*)d_in[2];
  const float* wq    = (const float*)d_in[3];
  const float* bq    = (const float*)d_in[4];
  const float* wk    = (const float*)d_in[5];
  const float* bk    = (const float*)d_in[6];
  const float* wv    = (const float*)d_in[7];
  const float* bv    = (const float*)d_in[8];
  const float* wp    = (const float*)d_in[9];
  const float* bp    = (const float*)d_in[10];
  float* outp = (float*)d_out;

  char* ws = (char*)d_ws;
  const size_t MB8 = (size_t)B_ * N_ * C_ * 2;   // 8 MB (bf16 tensor)
  float2* part = (float2*)(ws + 512);            // 4 KB
  ushort* qb   = (ushort*)(ws + 8192);
  ushort* kb   = (ushort*)(ws + 8192 + MB8);
  ushort* vtb  = (ushort*)(ws + 8192 + 2*MB8);   // [b][C][N-permuted per 32]
  ushort* Op   = (ushort*)(ws + 8192 + 3*MB8);   // SPLIT x 8MB partial O
  float*  lsum = (float*)(ws + 8192 + (3 + SPLIT)*MB8);  // SPLIT*B*N f32
  ushort* wt   = (ushort*)(ws + 8192 + (3 + SPLIT)*MB8 + (size_t)SPLIT*B_*N_*4);
  ushort* xnb  = (ushort*)(ws + 8192 + (3 + SPLIT)*MB8 + (size_t)SPLIT*B_*N_*4
                           + 4 * 16384 * sizeof(ushort));  // 8 MB bf16 gn(x)

  gnw<<<dim3(8, 68), 256, 0, stream>>>(x, wq, wk, wv, wp, part, wt);
  qkv_fused<<<512, 256, 0, stream>>>(x, part, gamma, beta, wt,
                                     bq, bk, bv, qb, kb, vtb, xnb);
  (void)hipFuncSetAttribute((const void*)attn_fwd,
                            hipFuncAttributeMaxDynamicSharedMemorySize, 32768);
  attn_fwd<<<dim3(32 * B_ * SPLIT), 256, 32768, stream>>>(qb, kb, vtb, Op, lsum);
  proj_res<<<512, 256, 0, stream>>>(Op, lsum, wt + 3 * 16384, bp, xnb, outp);
}

// Round 11
// 96.405 us; speedup vs baseline: 1.0370x; 1.0370x over previous
//
#include <hip/hip_runtime.h>
#include <hip/hip_bf16.h>

#define B_ 8
#define N_ 4096   // H*W
#define C_ 128
#define EPSV 1e-5f
#define SPLIT 2
#define KVB 64

using bf8   = __attribute__((ext_vector_type(8))) short;   // 8 bf16 (4 VGPRs)
using u16x8 = __attribute__((ext_vector_type(8))) ushort;
using f32x4 = __attribute__((ext_vector_type(4))) float;   // MFMA C/D

__device__ __forceinline__ ushort f2b(float f) {
  __hip_bfloat16 h = __float2bfloat16(f);
  return *reinterpret_cast<ushort*>(&h);
}
__device__ __forceinline__ float b2f(ushort u) {
  union { float f; unsigned x; } t; t.x = ((unsigned)u) << 16; return t.f;
}

// async global->LDS, 16B per lane; LDS dest is wave-uniform base + lane*16
__device__ __forceinline__ void gll16(const void* g, void* l) {
  __builtin_amdgcn_global_load_lds((const __attribute__((address_space(1))) void*)g,
                                   (__attribute__((address_space(3))) void*)l,
                                   16, 0, 0);
}

// ---------------- merged: GroupNorm partial stats + weight transpose ----------------
// blockIdx.y < 64: gn-partial path (bg = y, chunk = x)
// blockIdx.y >= 64: wtrans path, widx = y-64: wt[widx][n][el(k,n)] = bf16(w[k][n])
__global__ __launch_bounds__(256) void gnw(const float* __restrict__ x,
                                           const float* __restrict__ wq,
                                           const float* __restrict__ wk,
                                           const float* __restrict__ wv,
                                           const float* __restrict__ wp,
                                           float2* __restrict__ part,
                                           ushort* __restrict__ wt) {
  if (blockIdx.y >= 64) {
    const int widx = blockIdx.y - 64;
    const float* w = (widx == 0) ? wq : (widx == 1) ? wk : (widx == 2) ? wv : wp;
    ushort* o = wt + widx * 16384;
    const int r  = blockIdx.x * 16 + (threadIdx.x >> 4);   // k row 0..127
    const int c0 = (threadIdx.x & 15) << 3;                // n col base
    const float4 v0 = *reinterpret_cast<const float4*>(w + (size_t)r * C_ + c0);
    const float4 v1 = *reinterpret_cast<const float4*>(w + (size_t)r * C_ + c0 + 4);
    const float vv[8] = {v0.x, v0.y, v0.z, v0.w, v1.x, v1.y, v1.z, v1.w};
    #pragma unroll
    for (int j = 0; j < 8; ++j) {
      const int n = c0 + j;
      const int el = (r & 7) | ((((r >> 3)) ^ (n & 7)) << 3);
      o[(size_t)n * C_ + el] = f2b(vv[j]);
    }
    return;
  }
  const int bg = blockIdx.y;           // 0..63  (b*8+g)
  const int b = bg >> 3, g = bg & 7;
  const int chunk = blockIdx.x;        // 0..7
  const float* xp = x + (size_t)b * N_ * C_ + g * 16;
  float s = 0.f, s2 = 0.f;
  const int base4 = chunk * 2048;      // float4 index base
  for (int i = threadIdx.x; i < 2048; i += 256) {
    const int idx = base4 + i;
    const int n = idx >> 2, c4 = (idx & 3) << 2;
    const float4 v = *reinterpret_cast<const float4*>(xp + (size_t)n * C_ + c4);
    s  += v.x + v.y + v.z + v.w;
    s2 += v.x*v.x + v.y*v.y + v.z*v.z + v.w*v.w;
  }
  #pragma unroll
  for (int off = 32; off; off >>= 1) { s += __shfl_down(s, off); s2 += __shfl_down(s2, off); }
  __shared__ float red[8];
  const int wid = threadIdx.x >> 6;
  if ((threadIdx.x & 63) == 0) { red[wid] = s; red[4 + wid] = s2; }
  __syncthreads();
  if (threadIdx.x == 0)
    part[bg * 8 + chunk] = make_float2(red[0]+red[1]+red[2]+red[3],
                                       red[4]+red[5]+red[6]+red[7]);
}

// per-block inline group stats: mrs[g*2] = mean, mrs[g*2+1] = rsqrt(var+eps)
__device__ __forceinline__ void block_mrs(const float2* part, int b, int tid,
                                          float2* sp, float* mrs) {
  if (tid < 64) sp[tid] = part[b * 64 + tid];
  __syncthreads();
  if (tid < 8) {
    float s = 0.f, s2 = 0.f;
    #pragma unroll
    for (int c = 0; c < 8; ++c) { s += sp[tid*8+c].x; s2 += sp[tid*8+c].y; }
    const float inv = 1.f / 65536.f;
    const float m = s * inv;
    const float var = s2 * inv - m * m;
    mrs[tid*2]   = m;
    mrs[tid*2+1] = rsqrtf(var + EPSV);
  }
  __syncthreads();
}

// ---------------- fused GN + QKV projection (64-row tiles, 512 blocks) ----------------
// vtb is written with the kv axis PRE-PERMUTED within each 64-kv tile:
// o = kss*32 + hi*16 + lk*4 + r  ->  o' = kss*32 + lk*8 + hi*4 + r
// so attention's PV A-fragment (P values a lane holds after swapped QK^T)
// maps to one contiguous 16B LDS granule -> single ds_read_b128.
// ALSO stores gn(x) as bf16 (xnb) so proj_res skips the x re-read + GN recompute.
__global__ __launch_bounds__(256) void qkv_fused(const float* __restrict__ x,
                                                 const float2* __restrict__ part,
                                                 const float* __restrict__ gamma,
                                                 const float* __restrict__ beta,
                                                 const ushort* __restrict__ wt,
                                                 const float* __restrict__ bq,
                                                 const float* __restrict__ bk,
                                                 const float* __restrict__ bv,
                                                 ushort* __restrict__ qb, ushort* __restrict__ kb,
                                                 ushort* __restrict__ vtb,
                                                 ushort* __restrict__ xnb) {
  __shared__ ushort A[64][128];    // gn(x) tile, swizzled (octet ^= row&7)
  __shared__ ushort Bt[128][128];  // Bt[n][k] = w[k][n], swizzled
  __shared__ float2 sp[64];
  __shared__ float mrs[16];
  const int m0 = blockIdx.x * 64;
  const int tid = threadIdx.x;
  const int wid = tid >> 6, lane = tid & 63;
  block_mrs(part, m0 >> 12, tid, sp, mrs);
  for (int i = tid; i < 1024; i += 256) {
    const int row = i >> 4, c = (i & 15) << 3;
    const int grow = m0 + row;
    const float mm = mrs[(c >> 4) * 2], rr = mrs[(c >> 4) * 2 + 1];
    const float4 v0 = *reinterpret_cast<const float4*>(&x[(size_t)grow * C_ + c]);
    const float4 v1 = *reinterpret_cast<const float4*>(&x[(size_t)grow * C_ + c + 4]);
    const float vv[8] = {v0.x, v0.y, v0.z, v0.w, v1.x, v1.y, v1.z, v1.w};
    u16x8 u;
    #pragma unroll
    for (int j = 0; j < 8; ++j)
      u[j] = f2b((vv[j] - mm) * rr * gamma[c+j] + beta[c+j]);
    *reinterpret_cast<u16x8*>(&xnb[(size_t)grow * C_ + c]) = u;   // forward gn(x)
    const int el = ((c >> 3) ^ (row & 7)) << 3;
    *reinterpret_cast<u16x8*>(&A[row][el]) = u;
  }
  const int wm = wid >> 1, wn = wid & 1;
  const int lr = lane & 15, lk = lane >> 4;
  // 128^-0.5 * log2(e) folded into q (attention uses exp2)
  const float qscale = 0.12751749f;

  #pragma unroll 1
  for (int j = 0; j < 3; ++j) {
    const ushort* wtj = wt + j * 16384;       // [n][k] bf16, pre-swizzled
    const float* bias = (j == 0) ? bq : (j == 1) ? bk : bv;
    __syncthreads();   // previous compute's Bt reads done (A stage done on j=0)
    {
      ushort* bt0 = &Bt[0][0];
      #pragma unroll
      for (int c8 = 0; c8 < 8; ++c8) {
        const int ch = wid * 8 + c8;          // 32 chunks of 1KB
        gll16(wtj + ch * 512 + lane * 8, bt0 + ch * 512);
      }
    }
    __syncthreads();
    f32x4 acc[2][4] = {};
    #pragma unroll
    for (int ks = 0; ks < 4; ++ks) {
      const int g0 = ks * 4 + lk;
      bf8 af[2], bfv[4];
      #pragma unroll
      for (int mi = 0; mi < 2; ++mi) {
        const int row = wm * 32 + mi * 16 + lr;
        af[mi] = *reinterpret_cast<const bf8*>(&A[row][(g0 ^ (row & 7)) << 3]);
      }
      #pragma unroll
      for (int ni = 0; ni < 4; ++ni) {
        const int n = wn * 64 + ni * 16 + lr;
        bfv[ni] = *reinterpret_cast<const bf8*>(&Bt[n][(g0 ^ (n & 7)) << 3]);
      }
      #pragma unroll
      for (int mi = 0; mi < 2; ++mi)
        #pragma unroll
        for (int ni = 0; ni < 4; ++ni)
          acc[mi][ni] = __builtin_amdgcn_mfma_f32_16x16x32_bf16(af[mi], bfv[ni], acc[mi][ni], 0, 0, 0);
    }
    if (j < 2) {
      ushort* out = (j == 0) ? qb : kb;
      const float sc = (j == 0) ? qscale : 1.0f;
      #pragma unroll
      for (int mi = 0; mi < 2; ++mi)
        #pragma unroll
        for (int ni = 0; ni < 4; ++ni)
          #pragma unroll
          for (int r = 0; r < 4; ++r) {
            const int row = m0 + wm * 32 + mi * 16 + lk * 4 + r;
            const int col = wn * 64 + ni * 16 + lr;
            out[(size_t)row * C_ + col] = f2b((acc[mi][ni][r] + bias[col]) * sc);
          }
    } else {
      #pragma unroll
      for (int mi = 0; mi < 2; ++mi)
        #pragma unroll
        for (int ni = 0; ni < 4; ++ni) {
          const int rowb = m0 + wm * 32 + mi * 16 + lk * 4;
          const int col  = wn * 64 + ni * 16 + lr;
          const int bb = rowb >> 12, nn = rowb & 4095;
          // pi-permute kv within its 64-tile: bits [5]=kss [4]=hi [3:2]=lk [1:0]=r
          //   -> [5]=kss [4:3]=lk [2]=hi [1:0]=r   (r bits untouched: 4-store stays contiguous)
          const int o  = nn & 63;
          const int op = (o & 0x23) | ((o & 0x0C) << 1) | ((o & 0x10) >> 2);
          const int nnp = (nn & ~63) | op;
          const float bv2 = bias[col];
          ushort4 u;
          u.x = f2b(acc[mi][ni][0] + bv2);
          u.y = f2b(acc[mi][ni][1] + bv2);
          u.z = f2b(acc[mi][ni][2] + bv2);
          u.w = f2b(acc[mi][ni][3] + bv2);
          *reinterpret_cast<ushort4*>(&vtb[((size_t)bb * C_ + col) * N_ + nnp]) = u;
        }
    }
  }
}

// ---------------- Flash attention (no-max exp2, kv-split, double-buffered) ----------------
// BEST MEASURED STRUCTURE (attn 67.6us, total 96.4us): 2 blocks/CU, K+V both
// distance-1 double-buffered, P in-register via pre-permuted vtb, strength-
// reduced staging pointers. Occupancy probes (R5/R7/R10: 18->34%) left
// MfmaUtil pinned at 39-46% -> the limiter is the phase-locked barrier cadence
// + intra-wave serial chain, not occupancy; the fix is the full counted-vmcnt
// deep-pipeline combo (out of scope — null when grafted piecemeal).
// LDS 64KB dyn: K0@0 K1@8192 V0@16384 V1@24576 [ushort offsets]
__global__ __launch_bounds__(256, 2) void attn_fwd(const ushort* __restrict__ q,
                                                   const ushort* __restrict__ k,
                                                   const ushort* __restrict__ vt,
                                                   ushort* __restrict__ Op,
                                                   float* __restrict__ lsum) {
  extern __shared__ ushort smem[];
  const int bid = blockIdx.x;
  const int b   = bid & 7;            // batch == XCD (dispatch round-robin i%8)
  const int qi  = (bid >> 3) & 31;
  const int z   = bid >> 8;           // 0..SPLIT-1
  const int q0  = qi * 128;
  const int tid = threadIdx.x;
  const int w = tid >> 6, lane = tid & 63;
  const int lr = lane & 15, lk = lane >> 4;
  const ushort* qb = q  + (size_t)b * N_ * C_;
  const ushort* kb = k  + (size_t)b * N_ * C_;
  const ushort* vb = vt + (size_t)b * C_ * N_;   // [d][n-permuted]

  bf8 qf[2][4];
  #pragma unroll
  for (int h = 0; h < 2; ++h) {
    const int qrow = q0 + w * 32 + h * 16 + lr;
    #pragma unroll
    for (int ks = 0; ks < 4; ++ks)
      qf[h][ks] = *reinterpret_cast<const bf8*>(&qb[(size_t)qrow * C_ + ks * 32 + lk * 8]);
  }

  bf8 onesf;
  #pragma unroll
  for (int j = 0; j < 8; ++j) onesf[j] = (short)0x3F80;   // bf16 1.0

  f32x4 oacc[2][8] = {};
  f32x4 accl[2] = {};                 // l-sums via mfma(P, ones)

  const int t0 = z * 32;              // SPLIT=2: 32 tiles per block
  const int t1 = t0 + 32;

  // strength-reduced staging pointers: computed once, advanced by const stride
  const ushort* kg[4];
  const ushort* vg[4];
  #pragma unroll
  for (int j = 0; j < 4; ++j) {
    const int m = w * 4 + j;              // chunk 0..15 (1KB each)
    const int krow = m * 4 + (lane >> 4); // 0..63
    kg[j] = kb + (size_t)(t0 * KVB + krow) * C_ + (((lane & 15) ^ (krow & 7)) << 3);
    const int vrow = m * 8 + (lane >> 3); // 0..127
    vg[j] = vb + (size_t)vrow * N_ + t0 * KVB + (((lane & 7) ^ (vrow & 7)) << 3);
  }

  // stage current-pointer KV tile into buffer `sel`, then advance pointers
  auto STAGE = [&](int sel) {
    ushort* Kd = smem + sel * 8192;
    ushort* Vd = smem + 16384 + sel * 8192;
    #pragma unroll
    for (int j = 0; j < 4; ++j) {
      const int m = w * 4 + j;
      gll16(kg[j], Kd + m * 512);
      gll16(vg[j], Vd + m * 512);
    }
    #pragma unroll
    for (int j = 0; j < 4; ++j) { kg[j] += KVB * C_; vg[j] += KVB; }
  };

  STAGE(0);
  __builtin_amdgcn_s_setprio(1);
  #pragma unroll 1
  for (int kt = t0; kt < t1; ++kt) {
    const int cur = (kt - t0) & 1;
    // barrier: drains last iter's stage loads (in flight for a full compute
    // phase) and guarantees all waves done reading the buffer we stage next.
    __syncthreads();
    if (kt + 1 < t1) STAGE(cur ^ 1);

    const ushort* Kc = smem + cur * 8192;
    const ushort* Vc = smem + 16384 + cur * 8192;

    // S^T = K Q^T  (swapped operands: lane holds 4 consecutive kv per q-col)
    f32x4 s[2][4] = {};
    #pragma unroll
    for (int ks = 0; ks < 4; ++ks) {
      const int g0 = ks * 4 + lk;
      bf8 kf[4];
      #pragma unroll
      for (int ni = 0; ni < 4; ++ni) {
        const int n = ni * 16 + lr;
        kf[ni] = *reinterpret_cast<const bf8*>(&Kc[n * 128 + ((g0 ^ (n & 7)) << 3)]);
      }
      #pragma unroll
      for (int h = 0; h < 2; ++h)
        #pragma unroll
        for (int ni = 0; ni < 4; ++ni)
          s[h][ni] = __builtin_amdgcn_mfma_f32_16x16x32_bf16(kf[ni], qf[h][ks], s[h][ni], 0, 0, 0);
    }

    // P = exp2(S) in-register, packed into PV A-fragments (pi order matches
    // pre-permuted vtb granules).
    bf8 pa[2][2];
    #pragma unroll
    for (int kss = 0; kss < 2; ++kss)
      #pragma unroll
      for (int h = 0; h < 2; ++h) {
        bf8 t;
        #pragma unroll
        for (int hi = 0; hi < 2; ++hi) {
          const f32x4 sv = s[h][kss * 2 + hi];
          #pragma unroll
          for (int r = 0; r < 4; ++r)
            t[hi * 4 + r] = (short)f2b(__builtin_amdgcn_exp2f(sv[r]));
        }
        pa[kss][h] = t;
      }
    #pragma unroll
    for (int kss = 0; kss < 2; ++kss)
      #pragma unroll
      for (int h = 0; h < 2; ++h)
        accl[h] = __builtin_amdgcn_mfma_f32_16x16x32_bf16(pa[kss][h], onesf, accl[h], 0, 0, 0);

    // O += P V  (single b128 V read per (kss,ni), pre-permuted layout)
    bf8 vf[8];
    #pragma unroll
    for (int ni = 0; ni < 8; ++ni) {
      const int d = ni * 16 + lr;
      vf[ni] = *reinterpret_cast<const bf8*>(&Vc[d * 64 + ((lk ^ (d & 7)) << 3)]);
    }
    #pragma unroll
    for (int kss = 0; kss < 2; ++kss) {
      #pragma unroll
      for (int h = 0; h < 2; ++h)
        #pragma unroll
        for (int ni = 0; ni < 8; ++ni)
          oacc[h][ni] = __builtin_amdgcn_mfma_f32_16x16x32_bf16(pa[kss][h], vf[ni], oacc[h][ni], 0, 0, 0);
      if (kss == 0) {
        #pragma unroll
        for (int ni = 0; ni < 8; ++ni) {
          const int d = ni * 16 + lr;
          vf[ni] = *reinterpret_cast<const bf8*>(&Vc[d * 64 + (((4 + lk) ^ (d & 7)) << 3)]);
        }
      }
    }
  }
  __builtin_amdgcn_s_setprio(0);

  // l-sum lives in accl[h][r] for q-row lk*4+r (all lr cols identical)
  const size_t zb = (size_t)(z * B_ + b);
  if (lr == 0) {
    #pragma unroll
    for (int h = 0; h < 2; ++h)
      #pragma unroll
      for (int r = 0; r < 4; ++r)
        lsum[zb * N_ + q0 + w * 32 + h * 16 + lk * 4 + r] = accl[h][r];
  }
  ushort* ob = Op + zb * N_ * C_;
  #pragma unroll
  for (int h = 0; h < 2; ++h)
    #pragma unroll
    for (int ni = 0; ni < 8; ++ni)
      #pragma unroll
      for (int r = 0; r < 4; ++r) {
        const int row = q0 + w * 32 + h * 16 + lk * 4 + r;
        ob[(size_t)row * C_ + ni * 16 + lr] = f2b(oacc[h][ni][r]);
      }
}

// ---------------- output projection + residual (64-row tiles, combines partials) ----------------
// Residual xn comes from the forwarded bf16 xnb (written by qkv_fused) —
// no x re-read, no GN stats/recompute.
__global__ __launch_bounds__(256) void proj_res(const ushort* __restrict__ Op,
                                                const float* __restrict__ lsum,
                                                const ushort* __restrict__ wtp,
                                                const float* __restrict__ bias,
                                                const ushort* __restrict__ xnb,
                                                float* __restrict__ outp) {
  __shared__ ushort A[64][128];
  __shared__ ushort Bt[128][128];
  const int m0 = blockIdx.x * 64;
  const int tid = threadIdx.x;
  const int wid = tid >> 6, lane = tid & 63;
  const size_t BN = (size_t)B_ * N_;
  {
    ushort* bt0 = &Bt[0][0];
    #pragma unroll
    for (int c8 = 0; c8 < 8; ++c8) {
      const int ch = wid * 8 + c8;          // 32 chunks of 1KB
      gll16(wtp + ch * 512 + lane * 8, bt0 + ch * 512);
    }
  }
  for (int i = tid; i < 1024; i += 256) {
    const int row = i >> 4, c = (i & 15) << 3;
    const size_t grow = m0 + row;
    float l = 0.f;
    #pragma unroll
    for (int zz = 0; zz < SPLIT; ++zz) l += lsum[zz * BN + grow];
    const float inv = 1.f / l;
    float acc8[8] = {};
    #pragma unroll
    for (int zz = 0; zz < SPLIT; ++zz) {
      const u16x8 a = *reinterpret_cast<const u16x8*>(&Op[(zz * BN + grow) * C_ + c]);
      #pragma unroll
      for (int j = 0; j < 8; ++j) acc8[j] += b2f(a[j]);
    }
    u16x8 u;
    #pragma unroll
    for (int j = 0; j < 8; ++j) u[j] = f2b(acc8[j] * inv);
    const int el = ((c >> 3) ^ (row & 7)) << 3;
    *reinterpret_cast<u16x8*>(&A[row][el]) = u;
  }
  __syncthreads();
  const int wm = wid >> 1, wn = wid & 1;
  const int lr = lane & 15, lk = lane >> 4;
  f32x4 acc[2][4] = {};
  #pragma unroll
  for (int ks = 0; ks < 4; ++ks) {
    const int g0 = ks * 4 + lk;
    bf8 af[2], bfv[4];
    #pragma unroll
    for (int mi = 0; mi < 2; ++mi) {
      const int row = wm * 32 + mi * 16 + lr;
      af[mi] = *reinterpret_cast<const bf8*>(&A[row][(g0 ^ (row & 7)) << 3]);
    }
    #pragma unroll
    for (int ni = 0; ni < 4; ++ni) {
      const int n = wn * 64 + ni * 16 + lr;
      bfv[ni] = *reinterpret_cast<const bf8*>(&Bt[n][(g0 ^ (n & 7)) << 3]);
    }
    #pragma unroll
    for (int mi = 0; mi < 2; ++mi)
      #pragma unroll
      for (int ni = 0; ni < 4; ++ni)
        acc[mi][ni] = __builtin_amdgcn_mfma_f32_16x16x32_bf16(af[mi], bfv[ni], acc[mi][ni], 0, 0, 0);
  }
  #pragma unroll
  for (int mi = 0; mi < 2; ++mi)
    #pragma unroll
    for (int ni = 0; ni < 4; ++ni) {
      const int col = wn * 64 + ni * 16 + lr;
      const float bia = bias[col];
      #pragma unroll
      for (int r = 0; r < 4; ++r) {
        const int row = m0 + wm * 32 + mi * 16 + lk * 4 + r;
        const float xn = b2f(xnb[(size_t)row * C_ + col]);
        outp[(size_t)row * C_ + col] = xn + acc[mi][ni][r] + bia;
      }
    }
}

extern "C" void kernel_launch(void* const* d_in, const int* in_sizes, int n_in,
                              void* d_out, int out_size, void* d_ws, size_t ws_size,
                              hipStream_t stream) {
  const float* x     = (const float*)d_in[0];
  const float* gamma = (const float*)d_in[1];
  const float* beta  = (const float*)d_in[2];
  const float* wq    = (const float*)d_in[3];
  const float* bq    = (const float*)d_in[4];
  const float* wk    = (const float*)d_in[5];
  const float* bk    = (const float*)d_in[6];
  const float* wv    = (const float*)d_in[7];
  const float* bv    = (const float*)d_in[8];
  const float* wp    = (const float*)d_in[9];
  const float* bp    = (const float*)d_in[10];
  float* outp = (float*)d_out;

  char* ws = (char*)d_ws;
  const size_t MB8 = (size_t)B_ * N_ * C_ * 2;   // 8 MB (bf16 tensor)
  float2* part = (float2*)(ws + 512);            // 4 KB
  ushort* qb   = (ushort*)(ws + 8192);
  ushort* kb   = (ushort*)(ws + 8192 + MB8);
  ushort* vtb  = (ushort*)(ws + 8192 + 2*MB8);   // [b][C][N-permuted]
  ushort* Op   = (ushort*)(ws + 8192 + 3*MB8);   // SPLIT x 8MB partial O
  float*  lsum = (float*)(ws + 8192 + (3 + SPLIT)*MB8);  // SPLIT*B*N f32
  ushort* wt   = (ushort*)(ws + 8192 + (3 + SPLIT)*MB8 + (size_t)SPLIT*B_*N_*4);
  ushort* xnb  = (ushort*)(ws + 8192 + (3 + SPLIT)*MB8 + (size_t)SPLIT*B_*N_*4
                           + 4 * 16384 * sizeof(ushort));  // 8 MB bf16 gn(x)

  gnw<<<dim3(8, 68), 256, 0, stream>>>(x, wq, wk, wv, wp, part, wt);
  qkv_fused<<<512, 256, 0, stream>>>(x, part, gamma, beta, wt,
                                     bq, bk, bv, qb, kb, vtb, xnb);
  (void)hipFuncSetAttribute((const void*)attn_fwd,
                            hipFuncAttributeMaxDynamicSharedMemorySize, 65536);
  attn_fwd<<<dim3(32 * B_ * SPLIT), 256, 65536, stream>>>(qb, kb, vtb, Op, lsum);
  proj_res<<<512, 256, 0, stream>>>(Op, lsum, wt + 3 * 16384, bp, xnb, outp);
}